// Round 19
// baseline (244.290 us; speedup 1.0000x reference)
//
#include <hip/hip_runtime.h>
#include <stdint.h>
#include <stddef.h>

// ---------------------------------------------------------------------------
// GraphSAGE supervised forward (B=1024, D=HID=128, fanout 25/10, classes 64)
// Round 19: tail fused into gemm via device-scope done-counter (blocks
// 576..831 spin until all 832 epilogues land, then run tail rows).
// 2 launches: prologue (485 blk) -> fused gemm+tail (832x512).
// Prologue + gemm compute frozen from r18 (61.2us best).
// ---------------------------------------------------------------------------

typedef short bf16x8v __attribute__((ext_vector_type(8)));
typedef float f32x4v __attribute__((ext_vector_type(4)));

__host__ __device__ inline void tf2x32(uint32_t k0, uint32_t k1,
                                       uint32_t x0, uint32_t x1,
                                       uint32_t &o0, uint32_t &o1)
{
    uint32_t ks2 = k0 ^ k1 ^ 0x1BD11BDAu;
    uint32_t v0 = x0 + k0, v1 = x1 + k1;
#define TFR(d) { v0 += v1; v1 = (v1 << (d)) | (v1 >> (32 - (d))); v1 ^= v0; }
    TFR(13) TFR(15) TFR(26) TFR(6)   v0 += k1;  v1 += ks2 + 1u;
    TFR(17) TFR(29) TFR(16) TFR(24)  v0 += ks2; v1 += k0 + 2u;
    TFR(13) TFR(15) TFR(26) TFR(6)   v0 += k0;  v1 += k1 + 3u;
    TFR(17) TFR(29) TFR(16) TFR(24)  v0 += k1;  v1 += ks2 + 4u;
    TFR(13) TFR(15) TFR(26) TFR(6)   v0 += ks2; v1 += k0 + 5u;
#undef TFR
    o0 = v0; o1 = v1;
}

__device__ inline uint16_t f32_to_bf16_rne(float f)
{
    uint32_t u = __float_as_uint(f);
    u += 0x7FFFu + ((u >> 16) & 1u);
    return (uint16_t)(u >> 16);
}
__device__ inline float bf16_to_f32(uint16_t h)
{
    return __uint_as_float(((uint32_t)h) << 16);
}

// Prologue, one item per thread (r18-validated + done-counter zero):
//   [0,32768) W split; [32768,98304) zero m2; [98304,123904) sampling;
//   t==123904: zero done counter.
__global__ void prologue_kernel(const int* __restrict__ ids, const int* __restrict__ adj,
                                const float* __restrict__ Wx1, const float* __restrict__ Wn1,
                                uint16_t* __restrict__ xh, uint16_t* __restrict__ xl,
                                uint16_t* __restrict__ nh, uint16_t* __restrict__ nl,
                                uint32_t s0a, uint32_t s0b, uint32_t s1a, uint32_t s1b,
                                int* __restrict__ ids1, int* __restrict__ ids2,
                                float4* __restrict__ m2z, int* __restrict__ done)
{
    int t = blockIdx.x * 256 + threadIdx.x;
    if (t < 32768) {
        int k = (t & 16383) >> 7, n = t & 127;
        const float* W = (t < 16384) ? Wx1 : Wn1;
        uint16_t* H = (t < 16384) ? xh : nh;
        uint16_t* L = (t < 16384) ? xl : nl;
        float v = W[k * 128 + n];
        uint16_t h = f32_to_bf16_rne(v);
        uint16_t l = f32_to_bf16_rne(v - bf16_to_f32(h));
        H[n * 128 + k] = h;
        L[n * 128 + k] = l;
    } else if (t < 98304) {
        m2z[t - 32768] = make_float4(0.f, 0.f, 0.f, 0.f);
    } else if (t < 123904) {
        int j = t - 98304;                       // hop-1 row [0, 25600)
        uint32_t h, l;
        tf2x32(s0a, s0b, 0u, (uint32_t)j, h, l);
        int s1 = adj[(size_t)ids[j / 25] * 128u + ((h ^ l) & 127u)];
        ids1[j] = s1;
        const int* arow = adj + (size_t)s1 * 128u;
        int* o = ids2 + (size_t)j * 10;
#pragma unroll
        for (int u = 0; u < 10; ++u) {
            uint32_t hh, ll;
            tf2x32(s1a, s1b, 0u, (uint32_t)(j * 10 + u), hh, ll);
            o[u] = arow[(hh ^ ll) & 127u];
        }
    } else if (t == 123904) {
        *done = 0;
    }
}

// Fused gather+GEMM+tail: BM=64, BN=128, K=128, split-bf16 MFMA, 512 thr.
// vb<400: z1 (mean10 inline); vb<416: z3 (mean25); vb<816: z0; else z2.
// After epilogue: threadfence + done++. Blocks vb>=576 spin for done==832,
// then run tail row-block (vb-576): layer-2 GEMM + normalize + FC.
__launch_bounds__(512)
__global__ void gemm_fused(const float* __restrict__ feats, const int* __restrict__ ids,
                           const int* __restrict__ ids1, const int* __restrict__ ids2,
                           const uint16_t* __restrict__ xh, const uint16_t* __restrict__ xl,
                           const uint16_t* __restrict__ nh, const uint16_t* __restrict__ nl,
                           float* __restrict__ m2, float* __restrict__ h10,
                           const float* __restrict__ Wx2, const float* __restrict__ Wn2,
                           const float* __restrict__ fcw, const float* __restrict__ fcb,
                           float* __restrict__ out, int* __restrict__ done)
{
    __shared__ __align__(16) char smem[34816];
    uint16_t (*Ahi)[136] = reinterpret_cast<uint16_t(*)[136]>(smem);
    uint16_t (*Alo)[136] = reinterpret_cast<uint16_t(*)[136]>(smem + 17408);

    const int tid = threadIdx.x;
    const int vb = blockIdx.x;
    int z, bx;
    if (vb < 400)      { z = 1; bx = vb; }
    else if (vb < 416) { z = 3; bx = vb - 400; }
    else if (vb < 816) { z = 0; bx = vb - 416; }
    else               { z = 2; bx = vb - 816; }
    const int rb = bx * 64;
    const bool isX = (z == 0) || (z == 2);
    const uint16_t* WH = isX ? xh : nh;
    const uint16_t* WL = isX ? xl : nl;
    const int ccol0 = isX ? 0 : 128;

    const int lane = tid & 63;
    const int wv = tid >> 6;            // 0..7

    // ---- stage A (64 rows x 128 k = 2048 float4 chunks, bf16 hi/lo) ----
    if (isX) {
        const int* g = (z == 0) ? ids1 : ids;
#pragma unroll
        for (int i = 0; i < 4; ++i) {
            int s = tid + i * 512;
            int row = s >> 5, f4 = s & 31, k0 = f4 * 4;
            size_t arow = (size_t)g[rb + row];
            float4 v = *(const float4*)(feats + arow * 128 + k0);
            uint16_t h0 = f32_to_bf16_rne(v.x), h1 = f32_to_bf16_rne(v.y);
            uint16_t h2 = f32_to_bf16_rne(v.z), h3 = f32_to_bf16_rne(v.w);
            *(ushort4*)&Ahi[row][k0] = make_ushort4(h0, h1, h2, h3);
            *(ushort4*)&Alo[row][k0] = make_ushort4(f32_to_bf16_rne(v.x - bf16_to_f32(h0)),
                                                    f32_to_bf16_rne(v.y - bf16_to_f32(h1)),
                                                    f32_to_bf16_rne(v.z - bf16_to_f32(h2)),
                                                    f32_to_bf16_rne(v.w - bf16_to_f32(h3)));
        }
    } else {
        const int h = lane & 31;
        const int hw = tid >> 5;        // 0..15
        const int FAN = (z == 1) ? 10 : 25;
        const int* src = (z == 1) ? ids2 : ids1;
        const float sc = (z == 1) ? 0.1f : (1.0f / 25.0f);
        int idv[4];
#pragma unroll
        for (int j = 0; j < 4; ++j) {
            int r = rb + hw * 4 + j;
            idv[j] = (h < FAN) ? src[(size_t)r * FAN + h] : 0;
        }
#pragma unroll
        for (int j = 0; j < 4; ++j) {
            float a0 = 0.f, a1 = 0.f, a2 = 0.f, a3 = 0.f;
            if (z == 1) {
#pragma unroll
                for (int t = 0; t < 10; ++t) {
                    int id = __shfl(idv[j], (lane & 32) + t, 64);
                    float4 vv = *((const float4*)(feats + (size_t)id * 128) + h);
                    a0 += vv.x; a1 += vv.y; a2 += vv.z; a3 += vv.w;
                }
            } else {
#pragma unroll
                for (int t = 0; t < 25; ++t) {
                    int id = __shfl(idv[j], (lane & 32) + t, 64);
                    float4 vv = *((const float4*)(feats + (size_t)id * 128) + h);
                    a0 += vv.x; a1 += vv.y; a2 += vv.z; a3 += vv.w;
                }
            }
            a0 *= sc; a1 *= sc; a2 *= sc; a3 *= sc;
            uint16_t b0 = f32_to_bf16_rne(a0), b1 = f32_to_bf16_rne(a1);
            uint16_t b2 = f32_to_bf16_rne(a2), b3 = f32_to_bf16_rne(a3);
            int row = hw * 4 + j;
            *(ushort4*)&Ahi[row][h * 4] = make_ushort4(b0, b1, b2, b3);
            *(ushort4*)&Alo[row][h * 4] =
                make_ushort4(f32_to_bf16_rne(a0 - bf16_to_f32(b0)),
                             f32_to_bf16_rne(a1 - bf16_to_f32(b1)),
                             f32_to_bf16_rne(a2 - bf16_to_f32(b2)),
                             f32_to_bf16_rne(a3 - bf16_to_f32(b3)));
        }
    }
    __syncthreads();

    // ---- MFMA: 8 waves in 2x4 grid; each wave 32(M) x 32(N) ----
    const int wm = (wv >> 2) * 32;
    const int wn = (wv & 3) * 32;
    const int fr = lane & 15;
    const int kb = lane >> 4;

    f32x4v acc[2][2] = {};
#pragma unroll
    for (int ks = 0; ks < 4; ++ks) {
        const int kk = ks * 32 + kb * 8;
        bf16x8v aH[2], aL[2];
#pragma unroll
        for (int mi = 0; mi < 2; ++mi) {
            aH[mi] = *(const bf16x8v*)&Ahi[wm + mi * 16 + fr][kk];
            aL[mi] = *(const bf16x8v*)&Alo[wm + mi * 16 + fr][kk];
        }
#pragma unroll
        for (int ni = 0; ni < 2; ++ni) {
            size_t wrow = (size_t)(wn + ni * 16 + fr) * 128 + kk;
            bf16x8v bH = *(const bf16x8v*)(WH + wrow);
            bf16x8v bL = *(const bf16x8v*)(WL + wrow);
#pragma unroll
            for (int mi = 0; mi < 2; ++mi) {
                acc[mi][ni] = __builtin_amdgcn_mfma_f32_16x16x32_bf16(aH[mi], bH, acc[mi][ni], 0, 0, 0);
                acc[mi][ni] = __builtin_amdgcn_mfma_f32_16x16x32_bf16(aH[mi], bL, acc[mi][ni], 0, 0, 0);
                acc[mi][ni] = __builtin_amdgcn_mfma_f32_16x16x32_bf16(aL[mi], bH, acc[mi][ni], 0, 0, 0);
            }
        }
    }

    // ---- epilogue ----
    if (z < 2) {
        __syncthreads();
        float (*Red)[132] = reinterpret_cast<float(*)[132]>(smem);
#pragma unroll
        for (int mi = 0; mi < 2; ++mi)
#pragma unroll
            for (int ni = 0; ni < 2; ++ni) {
                int rl = wm + mi * 16 + kb * 4;
                int cl = wn + ni * 16 + fr;
#pragma unroll
                for (int r = 0; r < 4; ++r)
                    Red[rl + r][cl] = fmaxf(acc[mi][ni][r], 0.0f);
            }
        __syncthreads();
        int col = tid & 127;
        for (int gg = rb / 25 + (tid >> 7); gg * 25 < rb + 64; gg += 4) {
            int rs = max(gg * 25, rb), re = min(gg * 25 + 25, rb + 64);
            float s = 0.f;
            for (int r = rs; r < re; ++r) s += Red[r - rb][col];
            atomicAdd(&m2[(size_t)gg * 256 + ccol0 + col], s * (1.0f / 25.0f));
        }
    } else {
#pragma unroll
        for (int mi = 0; mi < 2; ++mi)
#pragma unroll
            for (int ni = 0; ni < 2; ++ni) {
                int orow = rb + wm + mi * 16 + kb * 4;
                int ocol = ccol0 + wn + ni * 16 + fr;
#pragma unroll
                for (int r = 0; r < 4; ++r)
                    h10[(size_t)(orow + r) * 256 + ocol] = fmaxf(acc[mi][ni][r], 0.0f);
            }
    }

    // ---- completion signal (all blocks) ----
    __syncthreads();
    __threadfence();                      // release: m2/h10 visible device-wide
    if (tid == 0) atomicAdd(done, 1);

    if (vb < 576) return;

    // ---- tail role: wait for all 832 epilogues, then 4 output rows ----
    if (tid == 0) {
        while (atomicAdd(done, 0) < 832) { }
    }
    __syncthreads();
    __threadfence();                      // acquire: see m2/h10

    float (*X)[260] = reinterpret_cast<float(*)[260]>(smem);
    float (*M)[260] = reinterpret_cast<float(*)[260]>(smem + 4160);
    float (*H)[260] = reinterpret_cast<float(*)[260]>(smem + 8320);
    const int r0 = (vb - 576) * 4;

    if (tid < 256) {
        int r = tid >> 6, q = tid & 63;
        *(float4*)&X[r][q * 4] = *((const float4*)(h10 + (size_t)(r0 + r) * 256) + q);
        *(float4*)&M[r][q * 4] = *((const float4*)(m2 + (size_t)(r0 + r) * 256) + q);
    }
    __syncthreads();

    if (tid < 256) {
        const float* W = (tid < 128) ? Wx2 : Wn2;
        const float (*S)[260] = (tid < 128) ? X : M;
        int c = tid & 127;
        float acc0 = 0.f, acc1 = 0.f, acc2 = 0.f, acc3 = 0.f;
        for (int k4 = 0; k4 < 256; k4 += 4) {
            float4 s0 = *(const float4*)&S[0][k4];
            float4 s1 = *(const float4*)&S[1][k4];
            float4 s2 = *(const float4*)&S[2][k4];
            float4 s3 = *(const float4*)&S[3][k4];
            float w0 = W[(size_t)(k4 + 0) * 128 + c];
            float w1 = W[(size_t)(k4 + 1) * 128 + c];
            float w2 = W[(size_t)(k4 + 2) * 128 + c];
            float w3 = W[(size_t)(k4 + 3) * 128 + c];
            acc0 = fmaf(s0.x, w0, fmaf(s0.y, w1, fmaf(s0.z, w2, fmaf(s0.w, w3, acc0))));
            acc1 = fmaf(s1.x, w0, fmaf(s1.y, w1, fmaf(s1.z, w2, fmaf(s1.w, w3, acc1))));
            acc2 = fmaf(s2.x, w0, fmaf(s2.y, w1, fmaf(s2.z, w2, fmaf(s2.w, w3, acc2))));
            acc3 = fmaf(s3.x, w0, fmaf(s3.y, w1, fmaf(s3.z, w2, fmaf(s3.w, w3, acc3))));
        }
        H[0][tid] = acc0; H[1][tid] = acc1; H[2][tid] = acc2; H[3][tid] = acc3;
    }
    __syncthreads();

    if (tid < 256) {
        const int w = tid >> 6, ln = tid & 63;
        float4 hv = *((const float4*)&H[w][0] + ln);
        float ss = hv.x * hv.x + hv.y * hv.y + hv.z * hv.z + hv.w * hv.w;
#pragma unroll
        for (int o = 32; o > 0; o >>= 1) ss += __shfl_xor(ss, o, 64);
        float scale = 1.0f / fmaxf(sqrtf(ss), 1e-12f);

        float acc = 0.f;
        for (int k4 = 0; k4 < 256; k4 += 4) {
            float4 h4 = *(const float4*)&H[w][k4];
            acc = fmaf(h4.x, fcw[(size_t)(k4 + 0) * 64 + ln],
                  fmaf(h4.y, fcw[(size_t)(k4 + 1) * 64 + ln],
                  fmaf(h4.z, fcw[(size_t)(k4 + 2) * 64 + ln],
                  fmaf(h4.w, fcw[(size_t)(k4 + 3) * 64 + ln], acc))));
        }
        out[(size_t)(r0 + w) * 64 + ln] = acc * scale + fcb[ln];
    }
}

extern "C" void kernel_launch(void* const* d_in, const int* in_sizes, int n_in,
                              void* d_out, int out_size, void* d_ws, size_t ws_size,
                              hipStream_t stream)
{
    const int*   ids   = (const int*)d_in[0];
    const float* feats = (const float*)d_in[1];
    const int*   adj   = (const int*)d_in[2];
    const float* W_x1  = (const float*)d_in[3];
    const float* W_n1  = (const float*)d_in[4];
    const float* W_x2  = (const float*)d_in[5];
    const float* W_n2  = (const float*)d_in[6];
    const float* fc_w  = (const float*)d_in[7];
    const float* fc_b  = (const float*)d_in[8];
    float* out = (float*)d_out;

    char* ws = (char*)d_ws;
    int*      ids1 = (int*)(ws + 0);            // 25600 x 4
    int*      ids2 = (int*)(ws + 102400);       // 256000 x 4
    float*    h10  = (float*)(ws + 1126400);    // 1024 x 256 f32
    float*    m2   = (float*)(ws + 2174976);    // 1024 x 256 f32 (atomics)
    uint16_t* xh   = (uint16_t*)(ws + 3223552); // W splits, 32,768 each
    uint16_t* xl   = (uint16_t*)(ws + 3256320);
    uint16_t* nh   = (uint16_t*)(ws + 3289088);
    uint16_t* nl   = (uint16_t*)(ws + 3321856);
    int*      done = (int*)(ws + 3354624);      // completion counter (4 B)

    // JAX PRNG key derivation (threefry2x32, partitionable foldlike):
    uint32_t f0a, f0b, f1a, f1b, s0a, s0b, s1a, s1b;
    tf2x32(0u, 42u, 0u, 0u, f0a, f0b);
    tf2x32(0u, 42u, 0u, 1u, f1a, f1b);
    tf2x32(f0a, f0b, 0u, 1u, s0a, s0b);
    tf2x32(f1a, f1b, 0u, 1u, s1a, s1b);

    // 1) prologue: W splits + m2 zero + sampling + done=0
    prologue_kernel<<<485, 256, 0, stream>>>(ids, adj, W_x1, W_n1,
                                             xh, xl, nh, nl,
                                             s0a, s0b, s1a, s1b,
                                             ids1, ids2, (float4*)m2, done);
    // 2) fused gather+GEMM+tail
    gemm_fused<<<832, 512, 0, stream>>>(feats, ids, ids1, ids2,
                                        xh, xl, nh, nl, m2, h10,
                                        W_x2, W_n2, fc_w, fc_b, out, done);
}

// Round 20
// 64.064 us; speedup vs baseline: 3.8132x; 3.8132x over previous
//
#include <hip/hip_runtime.h>
#include <stdint.h>
#include <stddef.h>

// ---------------------------------------------------------------------------
// GraphSAGE supervised forward (B=1024, D=HID=128, fanout 25/10, classes 64)
// Round 20: REVERT to r18 (61.2us, best validated). r19's spin-wait tail
// fusion collapsed throughput 4x (spinner waves starve producers; device-
// scope poll traffic) — inter-block sync in-kernel is a closed branch, as is
// cooperative launch (r5/r6). This 3-launch shape beat every alternative:
//   prologue (W split + per-row 2-hop sampling)
//   -> fused gather+GEMM (BM=64, 512thr: means computed in A-staging,
//      B direct from L2-resident pre-split weights, mean25 epilogue -> m2)
//   -> tail (layer-2 GEMM + normalize + FC).
// ---------------------------------------------------------------------------

typedef short bf16x8v __attribute__((ext_vector_type(8)));
typedef float f32x4v __attribute__((ext_vector_type(4)));

__host__ __device__ inline void tf2x32(uint32_t k0, uint32_t k1,
                                       uint32_t x0, uint32_t x1,
                                       uint32_t &o0, uint32_t &o1)
{
    uint32_t ks2 = k0 ^ k1 ^ 0x1BD11BDAu;
    uint32_t v0 = x0 + k0, v1 = x1 + k1;
#define TFR(d) { v0 += v1; v1 = (v1 << (d)) | (v1 >> (32 - (d))); v1 ^= v0; }
    TFR(13) TFR(15) TFR(26) TFR(6)   v0 += k1;  v1 += ks2 + 1u;
    TFR(17) TFR(29) TFR(16) TFR(24)  v0 += ks2; v1 += k0 + 2u;
    TFR(13) TFR(15) TFR(26) TFR(6)   v0 += k0;  v1 += k1 + 3u;
    TFR(17) TFR(29) TFR(16) TFR(24)  v0 += k1;  v1 += ks2 + 4u;
    TFR(13) TFR(15) TFR(26) TFR(6)   v0 += ks2; v1 += k0 + 5u;
#undef TFR
    o0 = v0; o1 = v1;
}

__device__ inline uint16_t f32_to_bf16_rne(float f)
{
    uint32_t u = __float_as_uint(f);
    u += 0x7FFFu + ((u >> 16) & 1u);
    return (uint16_t)(u >> 16);
}
__device__ inline float bf16_to_f32(uint16_t h)
{
    return __uint_as_float(((uint32_t)h) << 16);
}

// Prologue, one item per thread:
//   [0,32768)       W split-transpose -> xh/xl/nh/nl
//   [32768,98304)   zero m2 (float4)
//   [98304,123904)  j: hop-1 -> ids1[j], then 10x hop-2 -> ids2[10j..]
__global__ void prologue_kernel(const int* __restrict__ ids, const int* __restrict__ adj,
                                const float* __restrict__ Wx1, const float* __restrict__ Wn1,
                                uint16_t* __restrict__ xh, uint16_t* __restrict__ xl,
                                uint16_t* __restrict__ nh, uint16_t* __restrict__ nl,
                                uint32_t s0a, uint32_t s0b, uint32_t s1a, uint32_t s1b,
                                int* __restrict__ ids1, int* __restrict__ ids2,
                                float4* __restrict__ m2z)
{
    int t = blockIdx.x * 256 + threadIdx.x;
    if (t < 32768) {
        int k = (t & 16383) >> 7, n = t & 127;
        const float* W = (t < 16384) ? Wx1 : Wn1;
        uint16_t* H = (t < 16384) ? xh : nh;
        uint16_t* L = (t < 16384) ? xl : nl;
        float v = W[k * 128 + n];
        uint16_t h = f32_to_bf16_rne(v);
        uint16_t l = f32_to_bf16_rne(v - bf16_to_f32(h));
        H[n * 128 + k] = h;
        L[n * 128 + k] = l;
    } else if (t < 98304) {
        m2z[t - 32768] = make_float4(0.f, 0.f, 0.f, 0.f);
    } else if (t < 123904) {
        int j = t - 98304;                       // hop-1 row [0, 25600)
        uint32_t h, l;
        tf2x32(s0a, s0b, 0u, (uint32_t)j, h, l);
        int s1 = adj[(size_t)ids[j / 25] * 128u + ((h ^ l) & 127u)];
        ids1[j] = s1;
        const int* arow = adj + (size_t)s1 * 128u;
        int* o = ids2 + (size_t)j * 10;
#pragma unroll
        for (int u = 0; u < 10; ++u) {
            uint32_t hh, ll;
            tf2x32(s1a, s1b, 0u, (uint32_t)(j * 10 + u), hh, ll);
            o[u] = arow[(hh ^ ll) & 127u];
        }
    }
}

// Fused gather+GEMM: BM=64, BN=128, K=128, split-bf16 MFMA, 512 thr (8 waves).
// vb<400: z1 (mean10 inline, heavy, first); vb<416: z3 (mean25 inline);
// vb<816: z0 (gather ids1); else z2 (gather ids).
// z0/z1 -> mean25 epilogue atomicAdd m2; z2/z3 -> relu write h10.
__launch_bounds__(512)
__global__ void gemm_fused(const float* __restrict__ feats, const int* __restrict__ ids,
                           const int* __restrict__ ids1, const int* __restrict__ ids2,
                           const uint16_t* __restrict__ xh, const uint16_t* __restrict__ xl,
                           const uint16_t* __restrict__ nh, const uint16_t* __restrict__ nl,
                           float* __restrict__ m2, float* __restrict__ h10)
{
    __shared__ __align__(16) char smem[34816];
    uint16_t (*Ahi)[136] = reinterpret_cast<uint16_t(*)[136]>(smem);
    uint16_t (*Alo)[136] = reinterpret_cast<uint16_t(*)[136]>(smem + 17408);

    const int tid = threadIdx.x;
    const int vb = blockIdx.x;
    int z, bx;
    if (vb < 400)      { z = 1; bx = vb; }
    else if (vb < 416) { z = 3; bx = vb - 400; }
    else if (vb < 816) { z = 0; bx = vb - 416; }
    else               { z = 2; bx = vb - 816; }
    const int rb = bx * 64;
    const bool isX = (z == 0) || (z == 2);
    const uint16_t* WH = isX ? xh : nh;
    const uint16_t* WL = isX ? xl : nl;
    const int ccol0 = isX ? 0 : 128;

    const int lane = tid & 63;
    const int wv = tid >> 6;            // 0..7

    // ---- stage A (64 rows x 128 k = 2048 float4 chunks, bf16 hi/lo) ----
    if (isX) {                          // row gather + split: 4 chunks/thread
        const int* g = (z == 0) ? ids1 : ids;
#pragma unroll
        for (int i = 0; i < 4; ++i) {
            int s = tid + i * 512;      // 0..2047
            int row = s >> 5, f4 = s & 31, k0 = f4 * 4;
            size_t arow = (size_t)g[rb + row];
            float4 v = *(const float4*)(feats + arow * 128 + k0);
            uint16_t h0 = f32_to_bf16_rne(v.x), h1 = f32_to_bf16_rne(v.y);
            uint16_t h2 = f32_to_bf16_rne(v.z), h3 = f32_to_bf16_rne(v.w);
            *(ushort4*)&Ahi[row][k0] = make_ushort4(h0, h1, h2, h3);
            *(ushort4*)&Alo[row][k0] = make_ushort4(f32_to_bf16_rne(v.x - bf16_to_f32(h0)),
                                                    f32_to_bf16_rne(v.y - bf16_to_f32(h1)),
                                                    f32_to_bf16_rne(v.z - bf16_to_f32(h2)),
                                                    f32_to_bf16_rne(v.w - bf16_to_f32(h3)));
        }
    } else {
        // inline mean: 16 half-waves, each owns 4 rows; idv hoisted.
        const int h = lane & 31;
        const int hw = tid >> 5;        // 0..15
        const int FAN = (z == 1) ? 10 : 25;
        const int* src = (z == 1) ? ids2 : ids1;
        const float sc = (z == 1) ? 0.1f : (1.0f / 25.0f);
        int idv[4];
#pragma unroll
        for (int j = 0; j < 4; ++j) {
            int r = rb + hw * 4 + j;
            idv[j] = (h < FAN) ? src[(size_t)r * FAN + h] : 0;
        }
#pragma unroll
        for (int j = 0; j < 4; ++j) {
            float a0 = 0.f, a1 = 0.f, a2 = 0.f, a3 = 0.f;
            if (z == 1) {
#pragma unroll
                for (int t = 0; t < 10; ++t) {
                    int id = __shfl(idv[j], (lane & 32) + t, 64);
                    float4 vv = *((const float4*)(feats + (size_t)id * 128) + h);
                    a0 += vv.x; a1 += vv.y; a2 += vv.z; a3 += vv.w;
                }
            } else {
#pragma unroll
                for (int t = 0; t < 25; ++t) {
                    int id = __shfl(idv[j], (lane & 32) + t, 64);
                    float4 vv = *((const float4*)(feats + (size_t)id * 128) + h);
                    a0 += vv.x; a1 += vv.y; a2 += vv.z; a3 += vv.w;
                }
            }
            a0 *= sc; a1 *= sc; a2 *= sc; a3 *= sc;
            uint16_t b0 = f32_to_bf16_rne(a0), b1 = f32_to_bf16_rne(a1);
            uint16_t b2 = f32_to_bf16_rne(a2), b3 = f32_to_bf16_rne(a3);
            int row = hw * 4 + j;
            *(ushort4*)&Ahi[row][h * 4] = make_ushort4(b0, b1, b2, b3);
            *(ushort4*)&Alo[row][h * 4] =
                make_ushort4(f32_to_bf16_rne(a0 - bf16_to_f32(b0)),
                             f32_to_bf16_rne(a1 - bf16_to_f32(b1)),
                             f32_to_bf16_rne(a2 - bf16_to_f32(b2)),
                             f32_to_bf16_rne(a3 - bf16_to_f32(b3)));
        }
    }
    __syncthreads();

    // ---- MFMA: 8 waves in 2x4 grid; each wave 32(M) x 32(N) ----
    const int wm = (wv >> 2) * 32;
    const int wn = (wv & 3) * 32;
    const int fr = lane & 15;
    const int kb = lane >> 4;

    f32x4v acc[2][2] = {};
#pragma unroll
    for (int ks = 0; ks < 4; ++ks) {
        const int kk = ks * 32 + kb * 8;
        bf16x8v aH[2], aL[2];
#pragma unroll
        for (int mi = 0; mi < 2; ++mi) {
            aH[mi] = *(const bf16x8v*)&Ahi[wm + mi * 16 + fr][kk];
            aL[mi] = *(const bf16x8v*)&Alo[wm + mi * 16 + fr][kk];
        }
#pragma unroll
        for (int ni = 0; ni < 2; ++ni) {
            size_t wrow = (size_t)(wn + ni * 16 + fr) * 128 + kk;
            bf16x8v bH = *(const bf16x8v*)(WH + wrow);
            bf16x8v bL = *(const bf16x8v*)(WL + wrow);
#pragma unroll
            for (int mi = 0; mi < 2; ++mi) {
                acc[mi][ni] = __builtin_amdgcn_mfma_f32_16x16x32_bf16(aH[mi], bH, acc[mi][ni], 0, 0, 0);
                acc[mi][ni] = __builtin_amdgcn_mfma_f32_16x16x32_bf16(aH[mi], bL, acc[mi][ni], 0, 0, 0);
                acc[mi][ni] = __builtin_amdgcn_mfma_f32_16x16x32_bf16(aL[mi], bH, acc[mi][ni], 0, 0, 0);
            }
        }
    }

    // C/D layout: col = fr, row = kb*4 + reg.
    if (z < 2) {
        __syncthreads();
        float (*Red)[132] = reinterpret_cast<float(*)[132]>(smem);   // 64x132x4 = 33792 B
#pragma unroll
        for (int mi = 0; mi < 2; ++mi)
#pragma unroll
            for (int ni = 0; ni < 2; ++ni) {
                int rl = wm + mi * 16 + kb * 4;
                int cl = wn + ni * 16 + fr;
#pragma unroll
                for (int r = 0; r < 4; ++r)
                    Red[rl + r][cl] = fmaxf(acc[mi][ni][r], 0.0f);
            }
        __syncthreads();
        int col = tid & 127;
        for (int gg = rb / 25 + (tid >> 7); gg * 25 < rb + 64; gg += 4) {
            int rs = max(gg * 25, rb), re = min(gg * 25 + 25, rb + 64);
            float s = 0.f;
            for (int r = rs; r < re; ++r) s += Red[r - rb][col];
            atomicAdd(&m2[(size_t)gg * 256 + ccol0 + col], s * (1.0f / 25.0f));
        }
    } else {
#pragma unroll
        for (int mi = 0; mi < 2; ++mi)
#pragma unroll
            for (int ni = 0; ni < 2; ++ni) {
                int orow = rb + wm + mi * 16 + kb * 4;
                int ocol = ccol0 + wn + ni * 16 + fr;
#pragma unroll
                for (int r = 0; r < 4; ++r)
                    h10[(size_t)(orow + r) * 256 + ocol] = fmaxf(acc[mi][ni][r], 0.0f);
            }
    }
}

// Tail: layer-2 GEMM (K=256) + row-normalize + FC.
__launch_bounds__(256)
__global__ void tail_kernel(const float* __restrict__ h10, const float* __restrict__ m2,
                            const float* __restrict__ Wx2, const float* __restrict__ Wn2,
                            const float* __restrict__ fcw, const float* __restrict__ fcb,
                            float* __restrict__ out)
{
    __shared__ float X[4][260];
    __shared__ float M[4][260];
    __shared__ float H[4][260];
    const int tid = threadIdx.x;
    const int r0 = blockIdx.x * 4;

    {
        int r = tid >> 6, q = tid & 63;
        *(float4*)&X[r][q * 4] = *((const float4*)(h10 + (size_t)(r0 + r) * 256) + q);
        *(float4*)&M[r][q * 4] = *((const float4*)(m2 + (size_t)(r0 + r) * 256) + q);
    }
    __syncthreads();

    {
        const float* W = (tid < 128) ? Wx2 : Wn2;
        const float (*S)[260] = (tid < 128) ? X : M;
        int c = tid & 127;
        float acc0 = 0.f, acc1 = 0.f, acc2 = 0.f, acc3 = 0.f;
        for (int k4 = 0; k4 < 256; k4 += 4) {
            float4 s0 = *(const float4*)&S[0][k4];
            float4 s1 = *(const float4*)&S[1][k4];
            float4 s2 = *(const float4*)&S[2][k4];
            float4 s3 = *(const float4*)&S[3][k4];
            float w0 = W[(size_t)(k4 + 0) * 128 + c];
            float w1 = W[(size_t)(k4 + 1) * 128 + c];
            float w2 = W[(size_t)(k4 + 2) * 128 + c];
            float w3 = W[(size_t)(k4 + 3) * 128 + c];
            acc0 = fmaf(s0.x, w0, fmaf(s0.y, w1, fmaf(s0.z, w2, fmaf(s0.w, w3, acc0))));
            acc1 = fmaf(s1.x, w0, fmaf(s1.y, w1, fmaf(s1.z, w2, fmaf(s1.w, w3, acc1))));
            acc2 = fmaf(s2.x, w0, fmaf(s2.y, w1, fmaf(s2.z, w2, fmaf(s2.w, w3, acc2))));
            acc3 = fmaf(s3.x, w0, fmaf(s3.y, w1, fmaf(s3.z, w2, fmaf(s3.w, w3, acc3))));
        }
        H[0][tid] = acc0; H[1][tid] = acc1; H[2][tid] = acc2; H[3][tid] = acc3;
    }
    __syncthreads();

    const int w = tid >> 6, lane = tid & 63;
    float4 hv = *((const float4*)&H[w][0] + lane);
    float ss = hv.x * hv.x + hv.y * hv.y + hv.z * hv.z + hv.w * hv.w;
#pragma unroll
    for (int o = 32; o > 0; o >>= 1) ss += __shfl_xor(ss, o, 64);
    float scale = 1.0f / fmaxf(sqrtf(ss), 1e-12f);

    float acc = 0.f;
    for (int k4 = 0; k4 < 256; k4 += 4) {
        float4 h4 = *(const float4*)&H[w][k4];
        acc = fmaf(h4.x, fcw[(size_t)(k4 + 0) * 64 + lane],
              fmaf(h4.y, fcw[(size_t)(k4 + 1) * 64 + lane],
              fmaf(h4.z, fcw[(size_t)(k4 + 2) * 64 + lane],
              fmaf(h4.w, fcw[(size_t)(k4 + 3) * 64 + lane], acc))));
    }
    out[(size_t)(r0 + w) * 64 + lane] = acc * scale + fcb[lane];
}

extern "C" void kernel_launch(void* const* d_in, const int* in_sizes, int n_in,
                              void* d_out, int out_size, void* d_ws, size_t ws_size,
                              hipStream_t stream)
{
    const int*   ids   = (const int*)d_in[0];
    const float* feats = (const float*)d_in[1];
    const int*   adj   = (const int*)d_in[2];
    const float* W_x1  = (const float*)d_in[3];
    const float* W_n1  = (const float*)d_in[4];
    const float* W_x2  = (const float*)d_in[5];
    const float* W_n2  = (const float*)d_in[6];
    const float* fc_w  = (const float*)d_in[7];
    const float* fc_b  = (const float*)d_in[8];
    float* out = (float*)d_out;

    char* ws = (char*)d_ws;
    int*      ids1 = (int*)(ws + 0);            // 25600 x 4
    int*      ids2 = (int*)(ws + 102400);       // 256000 x 4
    float*    h10  = (float*)(ws + 1126400);    // 1024 x 256 f32
    float*    m2   = (float*)(ws + 2174976);    // 1024 x 256 f32 (atomics)
    uint16_t* xh   = (uint16_t*)(ws + 3223552); // W splits, 32,768 each
    uint16_t* xl   = (uint16_t*)(ws + 3256320);
    uint16_t* nh   = (uint16_t*)(ws + 3289088);
    uint16_t* nl   = (uint16_t*)(ws + 3321856); // end 3,354,624 B

    // JAX PRNG key derivation (threefry2x32, partitionable foldlike):
    uint32_t f0a, f0b, f1a, f1b, s0a, s0b, s1a, s1b;
    tf2x32(0u, 42u, 0u, 0u, f0a, f0b);
    tf2x32(0u, 42u, 0u, 1u, f1a, f1b);
    tf2x32(f0a, f0b, 0u, 1u, s0a, s0b);
    tf2x32(f1a, f1b, 0u, 1u, s1a, s1b);

    // 1) prologue: W splits + m2 zero + per-row hop-1 & hop-2 sampling
    prologue_kernel<<<484, 256, 0, stream>>>(ids, adj, W_x1, W_n1,
                                             xh, xl, nh, nl,
                                             s0a, s0b, s1a, s1b,
                                             ids1, ids2, (float4*)m2);
    // 2) fused gather+GEMM, BM=64 @ 512 threads (8 waves/block)
    gemm_fused<<<832, 512, 0, stream>>>(feats, ids, ids1, ids2,
                                        xh, xl, nh, nl, m2, h10);
    // 3) tail: layer-2 GEMM + normalize + FC
    tail_kernel<<<256, 256, 0, stream>>>(h10, m2, W_x2, W_n2, fc_w, fc_b, out);
}